// Round 1
// baseline (346.195 us; speedup 1.0000x reference)
//
#include <hip/hip_runtime.h>

#define Hh 64
#define Ww 64
#define Cc 512
#define Bb 16
#define NTOK (1 + Hh * Ww)   // 4097
#define TW 8                 // outputs per thread along w

// ---------------------------------------------------------------------------
// Prep kernel: combine w7 + (padded) w5 + (padded) w3 + identity delta into a
// single effective 7x7 kernel per channel, combine biases, and copy the cls
// tokens straight through to the output.
// ---------------------------------------------------------------------------
__global__ void ppeg_prep(const float* __restrict__ w7, const float* __restrict__ b7,
                          const float* __restrict__ w5, const float* __restrict__ b5,
                          const float* __restrict__ w3, const float* __restrict__ b3,
                          const float* __restrict__ x, float* __restrict__ weff,
                          float* __restrict__ beff, float* __restrict__ out) {
    int idx = blockIdx.x * blockDim.x + threadIdx.x;
    if (idx < Cc * 49) {
        int c = idx / 49, t = idx % 49;
        int r = t / 7, s = t % 7;
        float v = w7[idx];
        if (r >= 1 && r <= 5 && s >= 1 && s <= 5) v += w5[c * 25 + (r - 1) * 5 + (s - 1)];
        if (r >= 2 && r <= 4 && s >= 2 && s <= 4) v += w3[c * 9 + (r - 2) * 3 + (s - 2)];
        if (t == 24) v += 1.0f;   // identity (center tap)
        weff[idx] = v;
    }
    if (idx < Cc) beff[idx] = b7[idx] + b5[idx] + b3[idx];
    if (idx < Bb * Cc) {
        int b = idx / Cc, c = idx % Cc;
        size_t o = (size_t)b * NTOK * Cc + c;
        out[o] = x[o];   // cls token pass-through
    }
}

// ---------------------------------------------------------------------------
// Main conv kernel. Block = (64 channel-lanes, 4 rows). Each thread computes a
// 1x8 output row for one channel: 7 input rows x 14 cols streamed through
// registers, 49 combined taps held in registers (staged via LDS so global
// weight reads are coalesced).
// ---------------------------------------------------------------------------
__global__ __launch_bounds__(256, 4)
void ppeg_conv(const float* __restrict__ x, const float* __restrict__ weff,
               const float* __restrict__ beff, float* __restrict__ out) {
    __shared__ float wlds[64 * 49];
    __shared__ float blds[64];

    const int tx = threadIdx.x;        // channel lane 0..63 (wave = one (h,wtile))
    const int ty = threadIdx.y;        // row 0..3
    const int cb = blockIdx.y * 64;    // channel base
    const int b  = blockIdx.z;
    const int sp = blockIdx.x;         // 0..127 : 16 h-blocks x 8 w-tiles
    const int hblk  = sp >> 3;
    const int wblk  = sp & 7;
    const int h     = hblk * 4 + ty;
    const int wbase = wblk * TW;

    // Coalesced stage of this block's 64-channel combined-weight slab.
    const int lin = ty * 64 + tx;
    for (int i = lin; i < 64 * 49; i += 256)
        wlds[i] = weff[cb * 49 + i];
    if (lin < 64) blds[lin] = beff[cb + lin];
    __syncthreads();

    float wk[49];
#pragma unroll
    for (int k = 0; k < 49; ++k) wk[k] = wlds[tx * 49 + k];
    const float bias = blds[tx];

    const int c = cb + tx;
    const float* xb = x + ((size_t)b * NTOK + 1) * Cc + c;   // pixel (0,0), channel c

    float acc[TW];
#pragma unroll
    for (int j = 0; j < TW; ++j) acc[j] = bias;

    const bool interior = (wbase >= 3) && (wbase + TW + 3 <= Ww);

    if (interior) {
#pragma unroll
        for (int r = 0; r < 7; ++r) {
            const int hr = h + r - 3;
            if (hr < 0 || hr >= Hh) continue;   // wave-uniform (ty fixed per wave)
            const float* xrow = xb + ((size_t)hr * Ww + (wbase - 3)) * Cc;
            float v[TW + 6];
#pragma unroll
            for (int j = 0; j < TW + 6; ++j) v[j] = xrow[(size_t)j * Cc];
#pragma unroll
            for (int j = 0; j < TW; ++j)
#pragma unroll
                for (int s = 0; s < 7; ++s)
                    acc[j] = fmaf(wk[r * 7 + s], v[j + s], acc[j]);
        }
    } else {
#pragma unroll
        for (int r = 0; r < 7; ++r) {
            const int hr = h + r - 3;
            if (hr < 0 || hr >= Hh) continue;
            const float* xrow = xb + (size_t)hr * Ww * Cc;
            float v[TW + 6];
#pragma unroll
            for (int j = 0; j < TW + 6; ++j) {
                const int wc = wbase + j - 3;
                v[j] = (wc >= 0 && wc < Ww) ? xrow[(size_t)wc * Cc] : 0.0f;
            }
#pragma unroll
            for (int j = 0; j < TW; ++j)
#pragma unroll
                for (int s = 0; s < 7; ++s)
                    acc[j] = fmaf(wk[r * 7 + s], v[j + s], acc[j]);
        }
    }

    float* orow = out + ((size_t)b * NTOK + 1 + (size_t)h * Ww + wbase) * Cc + c;
#pragma unroll
    for (int j = 0; j < TW; ++j) orow[(size_t)j * Cc] = acc[j];
}

extern "C" void kernel_launch(void* const* d_in, const int* in_sizes, int n_in,
                              void* d_out, int out_size, void* d_ws, size_t ws_size,
                              hipStream_t stream) {
    const float* x  = (const float*)d_in[0];
    const float* w7 = (const float*)d_in[1];
    const float* b7 = (const float*)d_in[2];
    const float* w5 = (const float*)d_in[3];
    const float* b5 = (const float*)d_in[4];
    const float* w3 = (const float*)d_in[5];
    const float* b3 = (const float*)d_in[6];
    float* out = (float*)d_out;

    float* weff = (float*)d_ws;          // Cc*49 floats
    float* beff = weff + Cc * 49;        // Cc floats

    ppeg_prep<<<(Cc * 49 + 255) / 256, 256, 0, stream>>>(w7, b7, w5, b5, w3, b3,
                                                         x, weff, beff, out);

    dim3 grid((Ww / TW) * (Hh / 4), Cc / 64, Bb);   // (128, 8, 16)
    dim3 block(64, 4);
    ppeg_conv<<<grid, block, 0, stream>>>(x, weff, beff, out);
}